// Round 1
// baseline (432.223 us; speedup 1.0000x reference)
//
#include <hip/hip_runtime.h>

#define NPTS 4096
#define NBATCH 4
#define HDIM 192
#define CDIM 384

typedef _Float16 f16x8 __attribute__((ext_vector_type(8)));
typedef float f32x4 __attribute__((ext_vector_type(4)));

// ---------------- K0: W2 [192][384] f32 -> W2T [384][192] f16 ----------------
__global__ __launch_bounds__(256) void prep_w2(const float* __restrict__ W2,
                                               _Float16* __restrict__ W2T) {
  int i = blockIdx.x * 256 + threadIdx.x;
  if (i < HDIM * CDIM) {
    int h = i / CDIM, c = i % CDIM;   // consecutive threads -> consecutive c: coalesced read
    W2T[c * HDIM + h] = (_Float16)W2[i];
  }
}

// ---------------- K1: brute-force KNN, exact-match distances, stable ties ----------------
// block = 256 thr = 4 waves; 64 queries/block; wave w scans candidate quarter [w*1024,(w+1)*1024)
// per-lane sorted top-16 (strict <  => stable within quarter); 4-way merge (strict < => stable
// across quarters since quarter w has globally smaller indices than w+1).
__global__ __launch_bounds__(256) void knn_kernel(const float* __restrict__ pts,
                                                  int* __restrict__ idx_out) {
  __shared__ float smem[12288];            // 48KB: points x/y/z; aliased for merge lists after scan
  float* spx = smem;
  float* spy = smem + 4096;
  float* spz = smem + 8192;

  const int b  = blockIdx.x >> 6;          // 64 blocks per batch
  const int qb = (blockIdx.x & 63) << 6;
  const float* P = pts + (size_t)b * NPTS * 3;

  for (int i = threadIdx.x; i < NPTS; i += 256) {
    spx[i] = P[3 * i + 0];
    spy[i] = P[3 * i + 1];
    spz[i] = P[3 * i + 2];
  }
  __syncthreads();

  const int lane = threadIdx.x & 63;
  const int wv   = threadIdx.x >> 6;
  const int q    = qb + lane;
  const float qx = spx[q], qy = spy[q], qz = spz[q];

  float dl[16];
  int   il[16];
#pragma unroll
  for (int i = 0; i < 16; ++i) { dl[i] = 3.4e38f; il[i] = 0; }

  const int j0 = wv << 10;
  for (int jj = 0; jj < 1024; ++jj) {
    const int j = j0 + jj;
    const float dx = qx - spx[j];
    const float dy = qy - spy[j];
    const float dz = qz - spz[j];
    // EXACT match to numpy/jax: ((dx*dx + dy*dy) + dz*dz), f32, no FMA contraction
    const float d = __fadd_rn(__fadd_rn(__fmul_rn(dx, dx), __fmul_rn(dy, dy)),
                              __fmul_rn(dz, dz));
    if (__any(d < dl[15])) {
      const float v = (d < dl[15]) ? d : 3.4e38f;   // non-inserting lanes: identity insert
      bool cc[16];
#pragma unroll
      for (int i = 0; i < 16; ++i) cc[i] = v < dl[i];
#pragma unroll
      for (int i = 15; i >= 1; --i) {
        dl[i] = cc[i] ? (cc[i - 1] ? dl[i - 1] : v) : dl[i];
        il[i] = cc[i] ? (cc[i - 1] ? il[i - 1] : j) : il[i];
      }
      dl[0] = cc[0] ? v : dl[0];
      il[0] = cc[0] ? j : il[0];
    }
  }

  __syncthreads();            // points no longer needed; alias LDS for merge lists
  float* smd = smem;                        // [64 q][4 wave][16]
  int*   smi = (int*)(smem + 4096);
#pragma unroll
  for (int i = 0; i < 16; ++i) {
    smd[(lane * 4 + wv) * 16 + i] = dl[i];
    smi[(lane * 4 + wv) * 16 + i] = il[i];
  }
  __syncthreads();

  if (threadIdx.x < 64) {
    const int ql   = threadIdx.x;
    const int base = ql * 64;
    int p0 = 0, p1 = 0, p2 = 0, p3 = 0;
    int* op = idx_out + (((size_t)b * NPTS + qb + ql) << 4);
    for (int r = 0; r < 16; ++r) {
      // at loop entry total pops = r <= 15, so each p* <= 15: reads in-bounds
      const float d0 = smd[base +      p0];
      const float d1 = smd[base + 16 + p1];
      const float d2 = smd[base + 32 + p2];
      const float d3 = smd[base + 48 + p3];
      int bw = 0; float bd = d0;
      if (d1 < bd) { bd = d1; bw = 1; }    // strict <: ties prefer lower wave (lower index)
      if (d2 < bd) { bd = d2; bw = 2; }
      if (d3 < bd) { bd = d3; bw = 3; }
      const int bi = (bw == 0) ? smi[base + p0]
                   : (bw == 1) ? smi[base + 16 + p1]
                   : (bw == 2) ? smi[base + 32 + p2]
                               : smi[base + 48 + p3];
      op[r] = bi;
      p0 += (bw == 0); p1 += (bw == 1); p2 += (bw == 2); p3 += (bw == 3);
    }
  }
}

// ---------------- K2: fused layer1(swish, fp32) -> f16 MFMA layer2 -> maxpool ----------------
// block = 512 thr = 8 waves; 8 queries (=128 A-rows) per block.
// A staged in LDS [128][200] f16 (pad 192->200 halves: row stride 100 dwords, 100%32=4 -> 2-way only).
// Wave w computes channel tiles ct = w, w+8, w+16; B-frags streamed from W2T (f16, L2-resident).
__global__ __launch_bounds__(512) void mlp_kernel(const float* __restrict__ pts,
                                                  const int* __restrict__ idx,
                                                  const float* __restrict__ W1,
                                                  const float* __restrict__ b1,
                                                  const _Float16* __restrict__ W2T,
                                                  const float* __restrict__ b2,
                                                  float* __restrict__ out) {
  __shared__ _Float16 sA[128 * 200];       // 51.2 KB

  const int bid = blockIdx.x;
  const int b   = bid >> 9;                // 512 blocks per batch
  const int qb  = (bid & 511) << 3;
  const float* P = pts + (size_t)b * NPTS * 3;
  const int t = threadIdx.x;

  // ---- stage A = f16(swish(f @ W1 + b1)) : 128 rows x 192 h ----
  {
    const int row = t >> 2;                // 0..127 (4 threads per row)
    const int sub = t & 3;                 // 48 h-channels each
    const int ql  = row >> 4;
    const int kk  = row & 15;
    const int qq  = qb + ql;
    const int nb  = idx[(((size_t)b * NPTS + qq) << 4) + kk];
    const float pqx = P[qq * 3 + 0], pqy = P[qq * 3 + 1], pqz = P[qq * 3 + 2];
    const float f0 = P[nb * 3 + 0] - pqx;
    const float f1 = P[nb * 3 + 1] - pqy;
    const float f2 = P[nb * 3 + 2] - pqz;
    const int h0 = sub * 48;
#pragma unroll 4
    for (int hh = 0; hh < 48; ++hh) {
      const int h = h0 + hh;
      float a = b1[h] + f0 * W1[h]            + f1 * W1[HDIM + h]     + f2 * W1[2 * HDIM + h]
                      + pqx * W1[3 * HDIM + h] + pqy * W1[4 * HDIM + h] + pqz * W1[5 * HDIM + h];
      const float s = a * (1.0f / (1.0f + __expf(-a)));   // swish
      sA[row * 200 + h] = (_Float16)s;
    }
  }
  __syncthreads();

  // ---- MFMA phase ----
  const int lane = t & 63;
  const int wv   = t >> 6;                 // 0..7
  const int ln15 = lane & 15;
  const int kgr  = lane >> 4;              // 0..3

  for (int ct = wv; ct < 24; ct += 8) {
    f32x4 acc[8];
#pragma unroll
    for (int qi = 0; qi < 8; ++qi)
#pragma unroll
      for (int e = 0; e < 4; ++e) acc[qi][e] = 0.0f;

    const int c = ct * 16 + ln15;
#pragma unroll
    for (int kt = 0; kt < 6; ++kt) {
      const int k0 = kt * 32 + kgr * 8;
      const f16x8 bf = *(const f16x8*)(W2T + (size_t)c * HDIM + k0);  // coalesced 16B/lane
#pragma unroll
      for (int qi = 0; qi < 8; ++qi) {
        const f16x8 af = *(const f16x8*)(sA + (qi * 16 + ln15) * 200 + k0);
        acc[qi] = __builtin_amdgcn_mfma_f32_16x16x32_f16(af, bf, acc[qi], 0, 0, 0);
      }
    }

    const float bb = b2[c];
#pragma unroll
    for (int qi = 0; qi < 8; ++qi) {
      // C/D: col = lane&15 (=channel), row = (lane>>4)*4 + reg (=neighbor k) -> max over rows
      float m = fmaxf(fmaxf(acc[qi][0], acc[qi][1]), fmaxf(acc[qi][2], acc[qi][3]));
      m = fmaxf(m, __shfl_xor(m, 16));
      m = fmaxf(m, __shfl_xor(m, 32));
      if (lane < 16)
        out[((size_t)b * NPTS + qb + qi) * CDIM + c] = m + bb;
    }
  }
}

extern "C" void kernel_launch(void* const* d_in, const int* in_sizes, int n_in,
                              void* d_out, int out_size, void* d_ws, size_t ws_size,
                              hipStream_t stream) {
  const float* point = (const float*)d_in[0];
  const float* W1    = (const float*)d_in[1];
  const float* b1    = (const float*)d_in[2];
  const float* W2    = (const float*)d_in[3];
  const float* b2    = (const float*)d_in[4];
  // d_in[5] = k (always 16, hardcoded)

  int*      idx_ws = (int*)d_ws;                                // 4*4096*16*4 = 1 MB
  _Float16* W2T    = (_Float16*)((char*)d_ws + (1 << 20));      // 144 KB

  prep_w2<<<(HDIM * CDIM + 255) / 256, 256, 0, stream>>>(W2, W2T);
  knn_kernel<<<NBATCH * 64, 256, 0, stream>>>(point, idx_ws);
  mlp_kernel<<<NBATCH * 512, 512, 0, stream>>>(point, idx_ws, W1, b1, W2T, b2, (float*)d_out);
}